// Round 1
// baseline (189.667 us; speedup 1.0000x reference)
//
#include <hip/hip_runtime.h>
#include <math.h>

// Problem constants
#define M_ROWS   8192     // B*S
#define N_CODES  16384
#define D_DIM    32

// Tiling
#define R_TILE   16       // rows per block
#define C_TILE   256      // codes per LDS tile
#define NTHREADS 256
#define N_TILES  (N_CODES / C_TILE)   // 64

// Kernel A: cc[n] = sum_d codebook[n][d]^2
__global__ void vq_ccnorm_kernel(const float* __restrict__ cb,
                                 float* __restrict__ cc) {
    int n = blockIdx.x * blockDim.x + threadIdx.x;
    if (n < N_CODES) {
        const float* row = cb + (size_t)n * D_DIM;
        float s = 0.f;
#pragma unroll
        for (int d = 0; d < D_DIM; ++d) s = fmaf(row[d], row[d], s);
        cc[n] = s;
    }
}

// Main kernel: each block handles R_TILE rows vs all codes.
__global__ __launch_bounds__(NTHREADS, 2)
void vq_main_kernel(const float* __restrict__ z,
                    const float* __restrict__ codebook,
                    const float* __restrict__ cc,
                    float* __restrict__ zq_out,
                    float* __restrict__ idx_out) {
    __shared__ float zt[D_DIM][R_TILE];    // normalized z, transposed
    __shared__ float zz_s[R_TILE];         // sum zf^2 per row
    __shared__ float cbt[D_DIM][C_TILE];   // codebook tile, transposed
    __shared__ float cc_s[C_TILE];
    __shared__ int   idx_s[R_TILE];

    const int tid  = threadIdx.x;
    const int row0 = blockIdx.x * R_TILE;

    // ---- load z tile (16 rows x 32) into LDS ----
    {
        int r = tid >> 4;            // 0..15
        int d = (tid & 15) * 2;      // 0,2,...,30
        float2 v = *reinterpret_cast<const float2*>(&z[(size_t)(row0 + r) * D_DIM + d]);
        zt[d][r]     = v.x;
        zt[d + 1][r] = v.y;
    }
    __syncthreads();

    // ---- normalize rows (16 threads, one row each) ----
    if (tid < R_TILE) {
        float s = 0.f;
#pragma unroll
        for (int d = 0; d < D_DIM; ++d) { float v = zt[d][tid]; s = fmaf(v, v, s); }
        float norm = sqrtf(s);
        norm = fmaxf(norm, 1e-12f);
        float zzsum = 0.f;
#pragma unroll
        for (int d = 0; d < D_DIM; ++d) {
            float v = zt[d][tid] / norm;   // IEEE division to match reference
            zt[d][tid] = v;
            zzsum = fmaf(v, v, zzsum);
        }
        zz_s[tid] = zzsum;
    }
    __syncthreads();

    // ---- pull this thread's 2 rows into registers ----
    const int rg = tid >> 5;     // 0..7  (row group)
    const int cg = tid & 31;     // 0..31 (code group)
    const int lr0 = rg * 2;
    const int lr1 = lr0 + 1;

    float zr0[D_DIM], zr1[D_DIM];
#pragma unroll
    for (int d = 0; d < D_DIM; ++d) {
        float2 v = *reinterpret_cast<const float2*>(&zt[d][lr0]);
        zr0[d] = v.x;
        zr1[d] = v.y;
    }
    const float zza = zz_s[lr0];
    const float zzb = zz_s[lr1];

    float minv0 = 3.4e38f, minv1 = 3.4e38f;
    int   mini0 = 0,       mini1 = 0;

    for (int t = 0; t < N_TILES; ++t) {
        const int base = t * C_TILE;
        __syncthreads();   // previous iteration's reads of cbt/cc_s complete

        // ---- stage 256 codes: thread stages code (base+tid), transposed ----
        {
            const float4* src = reinterpret_cast<const float4*>(
                &codebook[(size_t)(base + tid) * D_DIM]);
#pragma unroll
            for (int k = 0; k < 8; ++k) {
                float4 v = src[k];
                cbt[k * 4 + 0][tid] = v.x;
                cbt[k * 4 + 1][tid] = v.y;
                cbt[k * 4 + 2][tid] = v.z;
                cbt[k * 4 + 3][tid] = v.w;
            }
            cc_s[tid] = cc[base + tid];
        }
        __syncthreads();

        // ---- compute 2 rows x 8 codes (codes cg*4..+3 and 128+cg*4..+3) ----
        float acc0[8], acc1[8];
#pragma unroll
        for (int j = 0; j < 8; ++j) { acc0[j] = 0.f; acc1[j] = 0.f; }

#pragma unroll
        for (int d = 0; d < D_DIM; ++d) {
            float4 ca = *reinterpret_cast<const float4*>(&cbt[d][cg * 4]);
            float4 cb = *reinterpret_cast<const float4*>(&cbt[d][cg * 4 + 128]);
            float a0 = zr0[d], a1 = zr1[d];
            acc0[0] = fmaf(a0, ca.x, acc0[0]);
            acc0[1] = fmaf(a0, ca.y, acc0[1]);
            acc0[2] = fmaf(a0, ca.z, acc0[2]);
            acc0[3] = fmaf(a0, ca.w, acc0[3]);
            acc0[4] = fmaf(a0, cb.x, acc0[4]);
            acc0[5] = fmaf(a0, cb.y, acc0[5]);
            acc0[6] = fmaf(a0, cb.z, acc0[6]);
            acc0[7] = fmaf(a0, cb.w, acc0[7]);
            acc1[0] = fmaf(a1, ca.x, acc1[0]);
            acc1[1] = fmaf(a1, ca.y, acc1[1]);
            acc1[2] = fmaf(a1, ca.z, acc1[2]);
            acc1[3] = fmaf(a1, ca.w, acc1[3]);
            acc1[4] = fmaf(a1, cb.x, acc1[4]);
            acc1[5] = fmaf(a1, cb.y, acc1[5]);
            acc1[6] = fmaf(a1, cb.z, acc1[6]);
            acc1[7] = fmaf(a1, cb.w, acc1[7]);
        }

        // ---- distances + argmin update ----
        float4 cca = *reinterpret_cast<const float4*>(&cc_s[cg * 4]);
        float4 ccb = *reinterpret_cast<const float4*>(&cc_s[cg * 4 + 128]);
        float ccv[8] = {cca.x, cca.y, cca.z, cca.w, ccb.x, ccb.y, ccb.z, ccb.w};
#pragma unroll
        for (int j = 0; j < 8; ++j) {
            int c = base + cg * 4 + (j < 4 ? j : 128 + (j - 4));
            // dist = (zz + cc) - 2*dot ; 2*dot is exact, single rounding via fma
            float t0 = zza + ccv[j];
            float d0 = fmaf(-2.f, acc0[j], t0);
            if (d0 < minv0) { minv0 = d0; mini0 = c; }
            float t1 = zzb + ccv[j];
            float d1 = fmaf(-2.f, acc1[j], t1);
            if (d1 < minv1) { minv1 = d1; mini1 = c; }
        }
    }

    // ---- reduce argmin across the 32 code-group lanes ----
#pragma unroll
    for (int off = 16; off >= 1; off >>= 1) {
        float ov0 = __shfl_xor(minv0, off);
        int   oi0 = __shfl_xor(mini0, off);
        if (ov0 < minv0 || (ov0 == minv0 && oi0 < mini0)) { minv0 = ov0; mini0 = oi0; }
        float ov1 = __shfl_xor(minv1, off);
        int   oi1 = __shfl_xor(mini1, off);
        if (ov1 < minv1 || (ov1 == minv1 && oi1 < mini1)) { minv1 = ov1; mini1 = oi1; }
    }
    if (cg == 0) {
        idx_s[lr0] = mini0;
        idx_s[lr1] = mini1;
    }
    __syncthreads();

    // ---- gather z_q = codebook[idx] and write outputs ----
    {
        int r  = tid >> 4;           // 0..15
        int d2 = (tid & 15) * 2;
        int gidx = idx_s[r];
        float2 v = *reinterpret_cast<const float2*>(&codebook[(size_t)gidx * D_DIM + d2]);
        *reinterpret_cast<float2*>(&zq_out[(size_t)(row0 + r) * D_DIM + d2]) = v;
    }
    if (tid < R_TILE) {
        idx_out[row0 + tid] = (float)idx_s[tid];
    }
}

extern "C" void kernel_launch(void* const* d_in, const int* in_sizes, int n_in,
                              void* d_out, int out_size, void* d_ws, size_t ws_size,
                              hipStream_t stream) {
    const float* z        = (const float*)d_in[0];   // [8,1024,32]
    const float* codebook = (const float*)d_in[1];   // [16384,32]
    float* out = (float*)d_out;
    float* zq_out  = out;                       // 262144 floats
    float* idx_out = out + (size_t)M_ROWS * D_DIM;   // 8192 floats
    float* cc = (float*)d_ws;                   // 16384 floats = 64 KB scratch

    vq_ccnorm_kernel<<<N_CODES / NTHREADS, NTHREADS, 0, stream>>>(codebook, cc);
    vq_main_kernel<<<M_ROWS / R_TILE, NTHREADS, 0, stream>>>(z, codebook, cc,
                                                             zq_out, idx_out);
}